// Round 1
// baseline (282.238 us; speedup 1.0000x reference)
//
#include <hip/hip_runtime.h>

#define NN 50000
#define NE 800000
#define D 128

#define CH 32              // edge chunks
#define EPC (NE / CH)      // 25000 edges per chunk
#define RG 8               // node ranges
#define NPR (NN / RG)      // 6250 nodes per range
#define CSRCAP (NE + 64)   // small tail guard for prefetch over-read

typedef short bf16x8 __attribute__((ext_vector_type(8)));
typedef float f32x4 __attribute__((ext_vector_type(4)));

// ---------------- bf16 helpers ----------------

__device__ __forceinline__ unsigned bf16rne(float f) {
  unsigned u = __float_as_uint(f);
  return (u + 0x7fffu + ((u >> 16) & 1u)) >> 16;
}
__device__ __forceinline__ unsigned packbf(float lo, float hi) {
  return bf16rne(lo) | (bf16rne(hi) << 16);
}

// fused: x->bf16 (blocks 0..6249), W^T bf16 x3 (blocks 6250..6441), zero row NN
__global__ __launch_bounds__(256) void cvtw_kernel(const float* __restrict__ x,
                                                   const float* __restrict__ W1,
                                                   const float* __restrict__ W2,
                                                   const float* __restrict__ W3,
                                                   unsigned short* __restrict__ hbf,
                                                   unsigned short* __restrict__ T1,
                                                   unsigned short* __restrict__ T2,
                                                   unsigned short* __restrict__ T3) {
  int b = blockIdx.x;
  int tid = threadIdx.x;
  if (b < 6250) {
    int i = b * 256 + tid;  // n4 = NN*D/4 = 1.6M exactly
    float4 v = ((const float4*)x)[i];
    uint2 p;
    p.x = packbf(v.x, v.y);
    p.y = packbf(v.z, v.w);
    ((uint2*)hbf)[i] = p;
  } else if (b < 6442) {
    int g = b - 6250;
    int w = g >> 6;
    int i = (g & 63) * 256 + tid;  // 0..16383
    const float* W = (w == 0) ? W1 : (w == 1) ? W2 : W3;
    unsigned short* T = (w == 0) ? T1 : (w == 1) ? T2 : T3;
    int n = i >> 7, k = i & 127;
    T[n * 128 + k] = (unsigned short)bf16rne(W[k * 128 + n]);
  } else {
    if (tid < 16) ((uint4*)(hbf + (size_t)NN * D))[tid] = make_uint4(0, 0, 0, 0);
  }
}

// ---------------- CSR build, no global atomics ----------------
__global__ __launch_bounds__(1024) void hist_kernel(const int* __restrict__ src,
                                                    const int* __restrict__ dst,
                                                    int* __restrict__ partial_dst,
                                                    int* __restrict__ partial_src) {
  __shared__ int hd[NPR];
  __shared__ int hs[NPR];
  int tid = threadIdx.x;
  int c = blockIdx.x >> 3;
  int r = blockIdx.x & 7;
  int base = r * NPR;
  for (int i = tid; i < NPR; i += 1024) { hd[i] = 0; hs[i] = 0; }
  __syncthreads();
  int e0 = c * EPC;
  for (int i = tid; i < EPC; i += 1024) {
    int d = dst[e0 + i];
    int s = src[e0 + i];
    unsigned dr = (unsigned)(d - base);
    unsigned sr = (unsigned)(s - base);
    if (dr < NPR) atomicAdd(&hd[dr], 1);
    if (sr < NPR) atomicAdd(&hs[sr], 1);
  }
  __syncthreads();
  for (int i = tid; i < NPR; i += 1024) {
    partial_dst[c * NN + base + i] = hd[i];
    partial_src[c * NN + base + i] = hs[i];
  }
}

__device__ __forceinline__ int block_excl_scan(int v, int* wsum) {
  int lane = threadIdx.x & 63;
  int w = threadIdx.x >> 6;
  int incl = v;
#pragma unroll
  for (int off = 1; off < 64; off <<= 1) {
    int t = __shfl_up(incl, off);
    if (lane >= off) incl += t;
  }
  if (lane == 63) wsum[w] = incl;
  __syncthreads();
  int wo = 0;
#pragma unroll
  for (int j = 0; j < 4; ++j)
    if (j < w) wo += wsum[j];
  return wo + incl - v;
}

// fused reduce + scan phase 1: chunk-prefix partial_dst in place, true in-deg
// -> degtmp, out-deg -> deg_out, block-exclusive-scan of degree (UNPADDED)
// -> row_ptr (local), block totals -> partials.
__global__ __launch_bounds__(256) void degscan_kernel(int* __restrict__ partial_dst,
                                                      const int* __restrict__ partial_src,
                                                      int* __restrict__ degtmp,
                                                      int* __restrict__ deg_out,
                                                      int* __restrict__ row_ptr,
                                                      int* __restrict__ partials, int N) {
  __shared__ int wsum[4];
  int d = blockIdx.x * 256 + threadIdx.x;
  int run = 0;
  if (d < N) {
#pragma unroll
    for (int c = 0; c < CH; ++c) {
      int v = partial_dst[c * NN + d];
      partial_dst[c * NN + d] = run;
      run += v;
    }
    degtmp[d] = run;
    int ro = 0;
#pragma unroll
    for (int c = 0; c < CH; ++c) ro += partial_src[c * NN + d];
    deg_out[d] = ro;
  }
  int excl = block_excl_scan(run, wsum);
  if (d < N) row_ptr[d] = excl;
  if (threadIdx.x == 255) partials[blockIdx.x] = excl + run;
}

__global__ __launch_bounds__(256) void scan2(int* __restrict__ partials,
                                             int* __restrict__ row_ptr, int nb, int N) {
  __shared__ int wsum[4];
  int v = (threadIdx.x < nb) ? partials[threadIdx.x] : 0;
  int excl = block_excl_scan(v, wsum);
  if (threadIdx.x < nb) partials[threadIdx.x] = excl;
  if (threadIdx.x == nb - 1) row_ptr[N] = excl + v;
}

__global__ __launch_bounds__(256) void scan3(int* __restrict__ row_ptr,
                                             const int* __restrict__ partials, int N) {
  int i = blockIdx.x * 256 + threadIdx.x;
  if (i < N) row_ptr[i] += partials[blockIdx.x];
}

__global__ __launch_bounds__(1024) void fill_kernel(const int* __restrict__ src,
                                                    const int* __restrict__ dst,
                                                    const int* __restrict__ row_ptr,
                                                    const int* __restrict__ partial_dst,
                                                    int* __restrict__ csr_src) {
  __shared__ int cur[NPR];
  int tid = threadIdx.x;
  int c = blockIdx.x >> 3;
  int r = blockIdx.x & 7;
  int base = r * NPR;
  for (int i = tid; i < NPR; i += 1024)
    cur[i] = row_ptr[base + i] + partial_dst[c * NN + base + i];
  __syncthreads();
  int e0 = c * EPC;
  for (int i = tid; i < EPC; i += 1024) {
    int d = dst[e0 + i];
    unsigned dr = (unsigned)(d - base);
    if (dr < NPR) {
      int pos = atomicAdd(&cur[dr], 1);
      csr_src[pos] = src[e0 + i];
    }
  }
}

// ---------------- aggregation: one wave per node, quarter-wave per edge ------
// UNPADDED CSR; tail slots predicated to the zero row NN via cndmask.
// 2-deep software pipeline: indices prefetched 2 iters ahead, rows 1 iter.
// bf16 in, f32 accumulate, bf16 out. MODE 0: sage. MODE 1: gcn rsqrt.
__device__ __forceinline__ void bacc(float* a, uint4 u) {
  a[0] += __uint_as_float(u.x << 16);
  a[1] += __uint_as_float(u.x & 0xffff0000u);
  a[2] += __uint_as_float(u.y << 16);
  a[3] += __uint_as_float(u.y & 0xffff0000u);
  a[4] += __uint_as_float(u.z << 16);
  a[5] += __uint_as_float(u.z & 0xffff0000u);
  a[6] += __uint_as_float(u.w << 16);
  a[7] += __uint_as_float(u.w & 0xffff0000u);
}

template <int MODE>
__global__ __launch_bounds__(256, 4) void agg_kernel(const unsigned short* __restrict__ hb,
                                                     const int* __restrict__ row_ptr,
                                                     const int* __restrict__ csr_src,
                                                     const int* __restrict__ degtmp,
                                                     unsigned short* __restrict__ outb, int N) {
  int wid = blockIdx.x * 4 + (threadIdx.x >> 6);
  int lane = threadIdx.x & 63;
  if (wid >= N) return;
  int start = row_ptr[wid];
  int deg = degtmp[wid];
  int iters = (deg + 15) >> 4;
  int q = lane >> 4;    // 0..3: which edge in the 4-group
  int col = lane & 15;  // 16B granule within row
  int dq = deg - q;     // guard: off < dq  <=>  off + q < deg
  const int* cp = csr_src + start + q;
  float a0[8] = {0, 0, 0, 0, 0, 0, 0, 0};
  float a1[8] = {0, 0, 0, 0, 0, 0, 0, 0};
  float a2[8] = {0, 0, 0, 0, 0, 0, 0, 0};
  float a3[8] = {0, 0, 0, 0, 0, 0, 0, 0};

  int n0 = NN, n1 = NN, n2 = NN, n3 = NN;
  uint4 c0 = make_uint4(0, 0, 0, 0), c1 = c0, c2 = c0, c3 = c0;

  auto loadidx = [&](int T) {
    int o = T * 16;
    int t0 = cp[o];
    int t1 = cp[o + 4];
    int t2 = cp[o + 8];
    int t3 = cp[o + 12];
    n0 = (o < dq) ? t0 : NN;
    n1 = (o + 4 < dq) ? t1 : NN;
    n2 = (o + 8 < dq) ? t2 : NN;
    n3 = (o + 12 < dq) ? t3 : NN;
  };
  auto loadrow = [&]() {
    c0 = ((const uint4*)(hb + (size_t)n0 * D))[col];
    c1 = ((const uint4*)(hb + (size_t)n1 * D))[col];
    c2 = ((const uint4*)(hb + (size_t)n2 * D))[col];
    c3 = ((const uint4*)(hb + (size_t)n3 * D))[col];
  };

  if (iters > 0) {
    loadidx(0);
    loadrow();
    if (iters > 1) loadidx(1);
#pragma unroll 1
    for (int t = 0; t + 1 < iters; ++t) {
      uint4 p0 = c0, p1 = c1, p2 = c2, p3 = c3;  // consume current (waits here)
      loadrow();                                 // issue rows for t+1
      if (t + 2 < iters) loadidx(t + 2);         // prefetch indices for t+2
      bacc(a0, p0);
      bacc(a1, p1);
      bacc(a2, p2);
      bacc(a3, p3);
    }
    bacc(a0, c0);
    bacc(a1, c1);
    bacc(a2, c2);
    bacc(a3, c3);
  }

#pragma unroll
  for (int j = 0; j < 8; ++j) a0[j] = (a0[j] + a1[j]) + (a2[j] + a3[j]);
#pragma unroll
  for (int j = 0; j < 8; ++j) {
    a0[j] += __shfl_xor(a0[j], 16);
    a0[j] += __shfl_xor(a0[j], 32);
  }
  if (MODE == 0) {
    uint4 s = ((const uint4*)(hb + (size_t)wid * D))[col];
    float sf[8] = {0, 0, 0, 0, 0, 0, 0, 0};
    bacc(sf, s);
    float inv = 1.0f / (float)(deg + 1);
#pragma unroll
    for (int j = 0; j < 8; ++j) a0[j] = (a0[j] + sf[j]) * inv;
  } else {
    float sc = rsqrtf(fmaxf((float)deg, 1.0f));
#pragma unroll
    for (int j = 0; j < 8; ++j) a0[j] *= sc;
  }
  if (q == 0) {
    uint4 p;
    p.x = packbf(a0[0], a0[1]);
    p.y = packbf(a0[2], a0[3]);
    p.z = packbf(a0[4], a0[5]);
    p.w = packbf(a0[6], a0[7]);
    ((uint4*)(outb + (size_t)wid * D))[col] = p;
  }
}

// ---------------- MFMA GEMM: [N x 128](bf16) @ [128 x 128] + bias ------------
// 256 thr = 4 waves; block tile 64 rows; wave tile 16 rows x 128 cols.
// MODE 1: scale rows by rsqrt(max(deg_out,1)). OUT_BF 1: write bf16 table.
template <int MODE, int OUT_BF>
__global__ __launch_bounds__(256) void mgemm_kernel(const unsigned short* __restrict__ A,
                                                    const unsigned short* __restrict__ WT,
                                                    const float* __restrict__ bias,
                                                    const int* __restrict__ deg_out,
                                                    float* __restrict__ outf,
                                                    unsigned short* __restrict__ outb, int N) {
  __shared__ unsigned short sWT[128 * 136];
  int tid = threadIdx.x;
  for (int g = tid; g < 2048; g += 256) {
    int n = g >> 4, c = g & 15;
    uint4 v = ((const uint4*)WT)[g];
    *(uint4*)&sWT[n * 136 + c * 8] = v;
  }
  int wv = tid >> 6;
  int lane = tid & 63;
  int q = lane >> 4;
  int ln = lane & 15;
  int row0 = blockIdx.x * 64 + wv * 16;
  int arow = row0 + ln;
  if (arow >= N) arow = 0;  // clamp; stores are guarded
  const unsigned short* Ar = A + (size_t)arow * 128 + q * 8;
  bf16x8 af0 = *(const bf16x8*)(Ar + 0);
  bf16x8 af1 = *(const bf16x8*)(Ar + 32);
  bf16x8 af2 = *(const bf16x8*)(Ar + 64);
  bf16x8 af3 = *(const bf16x8*)(Ar + 96);
  f32x4 acc[8];
#pragma unroll
  for (int t = 0; t < 8; ++t) acc[t] = (f32x4){0.f, 0.f, 0.f, 0.f};
  __syncthreads();
#pragma unroll
  for (int t = 0; t < 8; ++t) {
    const unsigned short* Wr = &sWT[(t * 16 + ln) * 136 + q * 8];
    bf16x8 b0 = *(const bf16x8*)(Wr + 0);
    bf16x8 b1 = *(const bf16x8*)(Wr + 32);
    bf16x8 b2 = *(const bf16x8*)(Wr + 64);
    bf16x8 b3 = *(const bf16x8*)(Wr + 96);
    acc[t] = __builtin_amdgcn_mfma_f32_16x16x32_bf16(af0, b0, acc[t], 0, 0, 0);
    acc[t] = __builtin_amdgcn_mfma_f32_16x16x32_bf16(af1, b1, acc[t], 0, 0, 0);
    acc[t] = __builtin_amdgcn_mfma_f32_16x16x32_bf16(af2, b2, acc[t], 0, 0, 0);
    acc[t] = __builtin_amdgcn_mfma_f32_16x16x32_bf16(af3, b3, acc[t], 0, 0, 0);
  }
  float scl[4];
#pragma unroll
  for (int r = 0; r < 4; ++r) {
    scl[r] = 1.0f;
    if (MODE == 1) {
      int row = row0 + q * 4 + r;
      int rr = (row < N) ? row : 0;
      scl[r] = rsqrtf(fmaxf((float)deg_out[rr], 1.0f));
    }
  }
#pragma unroll
  for (int t = 0; t < 8; ++t) {
    float b = bias[t * 16 + ln];
#pragma unroll
    for (int r = 0; r < 4; ++r) {
      int row = row0 + q * 4 + r;
      if (row < N) {
        float v = (acc[t][r] + b) * scl[r];
        if (OUT_BF)
          outb[(size_t)row * 128 + t * 16 + ln] = (unsigned short)bf16rne(v);
        else
          outf[(size_t)row * 128 + t * 16 + ln] = v;
      }
    }
  }
}

// ---------------- launcher ----------------

extern "C" void kernel_launch(void* const* d_in, const int* in_sizes, int n_in,
                              void* d_out, int out_size, void* d_ws, size_t ws_size,
                              hipStream_t stream) {
  const float* x = (const float*)d_in[0];
  const float* W1 = (const float*)d_in[1];
  const float* b1 = (const float*)d_in[2];
  const float* W2 = (const float*)d_in[3];
  const float* b2 = (const float*)d_in[4];
  const float* W3 = (const float*)d_in[5];
  const float* b3 = (const float*)d_in[6];
  const int* src = (const int*)d_in[7];
  const int* dst = (const int*)d_in[8];
  float* out = (float*)d_out;

  const int N = NN;

  // workspace layout (~46 MB)
  unsigned short* hbf = (unsigned short*)d_ws;             // (NN+1)*D bf16
  unsigned short* aggB = hbf + (size_t)(NN + 1) * D;       // NN*D bf16
  unsigned short* WT1 = aggB + (size_t)NN * D;             // 128*128 bf16
  unsigned short* WT2 = WT1 + D * D;
  unsigned short* WT3 = WT2 + D * D;
  int* partial_dst = (int*)(WT3 + D * D);                  // CH*NN
  int* partial_src = partial_dst + (size_t)CH * NN;        // CH*NN
  int* degtmp = partial_src + (size_t)CH * NN;             // NN
  int* deg_out = degtmp + NN;                              // NN
  int* row_ptr = deg_out + NN;                             // NN+1
  int* partials = row_ptr + NN + 1;                        // 256
  int* csr_src = partials + 256;                           // CSRCAP

  const int scanBlocks = (N + 255) / 256;  // 196

  cvtw_kernel<<<6443, 256, 0, stream>>>(x, W1, W2, W3, hbf, WT1, WT2, WT3);
  hist_kernel<<<CH * RG, 1024, 0, stream>>>(src, dst, partial_dst, partial_src);
  degscan_kernel<<<scanBlocks, 256, 0, stream>>>(partial_dst, partial_src, degtmp,
                                                 deg_out, row_ptr, partials, N);
  scan2<<<1, 256, 0, stream>>>(partials, row_ptr, scanBlocks, N);
  scan3<<<scanBlocks, 256, 0, stream>>>(row_ptr, partials, N);
  fill_kernel<<<CH * RG, 1024, 0, stream>>>(src, dst, row_ptr, partial_dst, csr_src);

  int aggBlocks = (N + 3) / 4;
  int gemmBlocks = (N + 63) / 64;

  // layer 1: sage(x)
  agg_kernel<0><<<aggBlocks, 256, 0, stream>>>(hbf, row_ptr, csr_src, degtmp, aggB, N);
  mgemm_kernel<0, 1><<<gemmBlocks, 256, 0, stream>>>(aggB, WT1, b1, deg_out, nullptr, hbf, N);
  // layer 2: sage(h1); fold norm_out for layer 3 into epilogue
  agg_kernel<0><<<aggBlocks, 256, 0, stream>>>(hbf, row_ptr, csr_src, degtmp, aggB, N);
  mgemm_kernel<1, 1><<<gemmBlocks, 256, 0, stream>>>(aggB, WT2, b2, deg_out, nullptr, hbf, N);
  // layer 3: gcn: (agg(h2*norm_out) * norm_in) @ W3 + b3
  agg_kernel<1><<<aggBlocks, 256, 0, stream>>>(hbf, row_ptr, csr_src, degtmp, aggB, N);
  mgemm_kernel<0, 0><<<gemmBlocks, 256, 0, stream>>>(aggB, WT3, b3, deg_out, out, nullptr, N);
}

// Round 2
// 268.388 us; speedup vs baseline: 1.0516x; 1.0516x over previous
//
#include <hip/hip_runtime.h>

#define NN 50000
#define NE 800000
#define D 128

#define CH 32              // edge chunks
#define EPC (NE / CH)      // 25000 edges per chunk
#define RGH 4              // node ranges (160KB LDS lets us halve the passes)
#define NPRH (NN / RGH)    // 12500 nodes per range
#define CSRCAP (NE + 16 * NN)

typedef short bf16x8 __attribute__((ext_vector_type(8)));
typedef float f32x4 __attribute__((ext_vector_type(4)));

// ---------------- bf16 helpers ----------------

__device__ __forceinline__ unsigned bf16rne(float f) {
  unsigned u = __float_as_uint(f);
  return (u + 0x7fffu + ((u >> 16) & 1u)) >> 16;
}
__device__ __forceinline__ unsigned packbf(float lo, float hi) {
  return bf16rne(lo) | (bf16rne(hi) << 16);
}

// fused: x->bf16 (blocks 0..6249), W^T bf16 x3 (blocks 6250..6441), zero row NN
__global__ __launch_bounds__(256) void cvtw_kernel(const float* __restrict__ x,
                                                   const float* __restrict__ W1,
                                                   const float* __restrict__ W2,
                                                   const float* __restrict__ W3,
                                                   unsigned short* __restrict__ hbf,
                                                   unsigned short* __restrict__ T1,
                                                   unsigned short* __restrict__ T2,
                                                   unsigned short* __restrict__ T3) {
  int b = blockIdx.x;
  int tid = threadIdx.x;
  if (b < 6250) {
    int i = b * 256 + tid;  // n4 = NN*D/4 = 1.6M exactly
    float4 v = ((const float4*)x)[i];
    uint2 p;
    p.x = packbf(v.x, v.y);
    p.y = packbf(v.z, v.w);
    ((uint2*)hbf)[i] = p;
  } else if (b < 6442) {
    int g = b - 6250;
    int w = g >> 6;
    int i = (g & 63) * 256 + tid;  // 0..16383
    const float* W = (w == 0) ? W1 : (w == 1) ? W2 : W3;
    unsigned short* T = (w == 0) ? T1 : (w == 1) ? T2 : T3;
    int n = i >> 7, k = i & 127;
    T[n * 128 + k] = (unsigned short)bf16rne(W[k * 128 + n]);
  } else {
    if (tid < 16) ((uint4*)(hbf + (size_t)NN * D))[tid] = make_uint4(0, 0, 0, 0);
  }
}

// ---------------- CSR build, no global atomics ----------------
// RGH=4: 100KB LDS (hd+hs) -> edge list read 4x instead of 8x.
__global__ __launch_bounds__(1024) void hist_kernel(const int* __restrict__ src,
                                                    const int* __restrict__ dst,
                                                    int* __restrict__ partial_dst,
                                                    int* __restrict__ partial_src) {
  __shared__ int hd[NPRH];
  __shared__ int hs[NPRH];
  int tid = threadIdx.x;
  int c = blockIdx.x >> 2;
  int r = blockIdx.x & 3;
  int base = r * NPRH;
  for (int i = tid; i < NPRH; i += 1024) { hd[i] = 0; hs[i] = 0; }
  __syncthreads();
  int e0 = c * EPC;
  for (int i = tid; i < EPC; i += 1024) {
    int d = dst[e0 + i];
    int s = src[e0 + i];
    unsigned dr = (unsigned)(d - base);
    unsigned sr = (unsigned)(s - base);
    if (dr < NPRH) atomicAdd(&hd[dr], 1);
    if (sr < NPRH) atomicAdd(&hs[sr], 1);
  }
  __syncthreads();
  for (int i = tid; i < NPRH; i += 1024) {
    partial_dst[c * NN + base + i] = hd[i];
    partial_src[c * NN + base + i] = hs[i];
  }
}

__device__ __forceinline__ int block_excl_scan(int v, int* wsum) {
  int lane = threadIdx.x & 63;
  int w = threadIdx.x >> 6;
  int incl = v;
#pragma unroll
  for (int off = 1; off < 64; off <<= 1) {
    int t = __shfl_up(incl, off);
    if (lane >= off) incl += t;
  }
  if (lane == 63) wsum[w] = incl;
  __syncthreads();
  int wo = 0;
#pragma unroll
  for (int j = 0; j < 4; ++j)
    if (j < w) wo += wsum[j];
  return wo + incl - v;
}

// fused reduce + scan phase 1: chunk-prefix partial_dst in place, true in-deg
// -> degtmp, out-deg -> deg_out, block-exclusive-scan of PADDED degree
// (ceil16) -> row_ptr (local), block totals -> partials.
__global__ __launch_bounds__(256) void degscan_kernel(int* __restrict__ partial_dst,
                                                      const int* __restrict__ partial_src,
                                                      int* __restrict__ degtmp,
                                                      int* __restrict__ deg_out,
                                                      int* __restrict__ row_ptr,
                                                      int* __restrict__ partials, int N) {
  __shared__ int wsum[4];
  int d = blockIdx.x * 256 + threadIdx.x;
  int run = 0;
  if (d < N) {
#pragma unroll
    for (int c = 0; c < CH; ++c) {
      int v = partial_dst[c * NN + d];
      partial_dst[c * NN + d] = run;
      run += v;
    }
    degtmp[d] = run;
    int ro = 0;
#pragma unroll
    for (int c = 0; c < CH; ++c) ro += partial_src[c * NN + d];
    deg_out[d] = ro;
  }
  int pad = (run + 15) & ~15;
  int excl = block_excl_scan(pad, wsum);
  if (d < N) row_ptr[d] = excl;
  if (threadIdx.x == 255) partials[blockIdx.x] = excl + pad;
}

__global__ __launch_bounds__(256) void scan2(int* __restrict__ partials,
                                             int* __restrict__ row_ptr, int nb, int N) {
  __shared__ int wsum[4];
  int v = (threadIdx.x < nb) ? partials[threadIdx.x] : 0;
  int excl = block_excl_scan(v, wsum);
  if (threadIdx.x < nb) partials[threadIdx.x] = excl;
  if (threadIdx.x == nb - 1) row_ptr[N] = excl + v;
}

__global__ __launch_bounds__(256) void scan3(int* __restrict__ row_ptr,
                                             const int* __restrict__ partials, int N) {
  int i = blockIdx.x * 256 + threadIdx.x;
  if (i < N) row_ptr[i] += partials[blockIdx.x];
}

__global__ __launch_bounds__(1024) void fill_kernel(const int* __restrict__ src,
                                                    const int* __restrict__ dst,
                                                    const int* __restrict__ row_ptr,
                                                    const int* __restrict__ partial_dst,
                                                    int* __restrict__ csr_src) {
  __shared__ int cur[NPRH];
  int tid = threadIdx.x;
  int c = blockIdx.x >> 2;
  int r = blockIdx.x & 3;
  int base = r * NPRH;
  for (int i = tid; i < NPRH; i += 1024)
    cur[i] = row_ptr[base + i] + partial_dst[c * NN + base + i];
  __syncthreads();
  int e0 = c * EPC;
  for (int i = tid; i < EPC; i += 1024) {
    int d = dst[e0 + i];
    unsigned dr = (unsigned)(d - base);
    if (dr < NPRH) {
      int pos = atomicAdd(&cur[dr], 1);
      csr_src[pos] = src[e0 + i];
    }
  }
}

// write dummy index NN into each row's pad tail [row_ptr[i]+deg, row_ptr[i+1])
__global__ __launch_bounds__(256) void pad_kernel(const int* __restrict__ row_ptr,
                                                  const int* __restrict__ degtmp,
                                                  int* __restrict__ csr_src, int N) {
  int i = blockIdx.x * 256 + threadIdx.x;
  if (i >= N) return;
  int s = row_ptr[i] + degtmp[i];
  int e = row_ptr[i + 1];
  for (int j = s; j < e; ++j) csr_src[j] = NN;
}

// ---------------- aggregation: one wave per node, quarter-wave per edge ------
// Rows padded to x16 edges -> single branch-free loop (avg iters ~1.5).
// Occupancy-tuned: 2 accumulator banks (16 f32) + hoisted self/deg loads keep
// VGPR <= 64 so __launch_bounds__(256,8) doubles resident waves (latency-bound
// gather). bf16 in, f32 accumulate, bf16 out. MODE 0: sage. MODE 1: gcn rsqrt.
__device__ __forceinline__ void bacc(float* a, uint4 u) {
  a[0] += __uint_as_float(u.x << 16);
  a[1] += __uint_as_float(u.x & 0xffff0000u);
  a[2] += __uint_as_float(u.y << 16);
  a[3] += __uint_as_float(u.y & 0xffff0000u);
  a[4] += __uint_as_float(u.z << 16);
  a[5] += __uint_as_float(u.z & 0xffff0000u);
  a[6] += __uint_as_float(u.w << 16);
  a[7] += __uint_as_float(u.w & 0xffff0000u);
}

template <int MODE>
__global__ __launch_bounds__(256, 8) void agg_kernel(const unsigned short* __restrict__ hb,
                                                     const int* __restrict__ row_ptr,
                                                     const int* __restrict__ csr_src,
                                                     const int* __restrict__ degtmp,
                                                     unsigned short* __restrict__ outb, int N) {
  int wid = blockIdx.x * 4 + (threadIdx.x >> 6);
  int lane = threadIdx.x & 63;
  if (wid >= N) return;
  int start = row_ptr[wid];
  int iters = (row_ptr[wid + 1] - start) >> 4;
  int indeg = degtmp[wid];  // hoisted: issue early, consume in epilogue
  int q = lane >> 4;        // 0..3: which edge in the 4-group
  int col = lane & 15;      // 16B granule within row
  // self row: issue before the loop so it overlaps the gather chain
  uint4 sr = make_uint4(0, 0, 0, 0);
  if (MODE == 0) sr = ((const uint4*)(hb + (size_t)wid * D))[col];
  float a0[8] = {0, 0, 0, 0, 0, 0, 0, 0};
  float a1[8] = {0, 0, 0, 0, 0, 0, 0, 0};
  const int* ce = csr_src + start + q;
  for (int it = 0; it < iters; ++it, ce += 16) {
    int i0 = ce[0];
    int i1 = ce[4];
    int i2 = ce[8];
    int i3 = ce[12];
    uint4 u0 = ((const uint4*)(hb + (size_t)i0 * D))[col];
    uint4 u1 = ((const uint4*)(hb + (size_t)i1 * D))[col];
    uint4 u2 = ((const uint4*)(hb + (size_t)i2 * D))[col];
    uint4 u3 = ((const uint4*)(hb + (size_t)i3 * D))[col];
    bacc(a0, u0);
    bacc(a1, u1);
    bacc(a0, u2);
    bacc(a1, u3);
  }
#pragma unroll
  for (int j = 0; j < 8; ++j) a0[j] += a1[j];
#pragma unroll
  for (int j = 0; j < 8; ++j) {
    a0[j] += __shfl_xor(a0[j], 16);
    a0[j] += __shfl_xor(a0[j], 32);
  }
  if (MODE == 0) {
    float sf[8] = {0, 0, 0, 0, 0, 0, 0, 0};
    bacc(sf, sr);
    float inv = 1.0f / (float)(indeg + 1);
#pragma unroll
    for (int j = 0; j < 8; ++j) a0[j] = (a0[j] + sf[j]) * inv;
  } else {
    float sc = rsqrtf(fmaxf((float)indeg, 1.0f));
#pragma unroll
    for (int j = 0; j < 8; ++j) a0[j] *= sc;
  }
  if (q == 0) {
    uint4 p;
    p.x = packbf(a0[0], a0[1]);
    p.y = packbf(a0[2], a0[3]);
    p.z = packbf(a0[4], a0[5]);
    p.w = packbf(a0[6], a0[7]);
    ((uint4*)(outb + (size_t)wid * D))[col] = p;
  }
}

// ---------------- MFMA GEMM: [N x 128](bf16) @ [128 x 128] + bias ------------
// 256 thr = 4 waves; block tile 64 rows; wave tile 16 rows x 128 cols.
// MODE 1: scale rows by rsqrt(max(deg_out,1)). OUT_BF 1: write bf16 table.
template <int MODE, int OUT_BF>
__global__ __launch_bounds__(256) void mgemm_kernel(const unsigned short* __restrict__ A,
                                                    const unsigned short* __restrict__ WT,
                                                    const float* __restrict__ bias,
                                                    const int* __restrict__ deg_out,
                                                    float* __restrict__ outf,
                                                    unsigned short* __restrict__ outb, int N) {
  __shared__ unsigned short sWT[128 * 136];
  int tid = threadIdx.x;
  for (int g = tid; g < 2048; g += 256) {
    int n = g >> 4, c = g & 15;
    uint4 v = ((const uint4*)WT)[g];
    *(uint4*)&sWT[n * 136 + c * 8] = v;
  }
  int wv = tid >> 6;
  int lane = tid & 63;
  int q = lane >> 4;
  int ln = lane & 15;
  int row0 = blockIdx.x * 64 + wv * 16;
  int arow = row0 + ln;
  if (arow >= N) arow = 0;  // clamp; stores are guarded
  const unsigned short* Ar = A + (size_t)arow * 128 + q * 8;
  bf16x8 af0 = *(const bf16x8*)(Ar + 0);
  bf16x8 af1 = *(const bf16x8*)(Ar + 32);
  bf16x8 af2 = *(const bf16x8*)(Ar + 64);
  bf16x8 af3 = *(const bf16x8*)(Ar + 96);
  f32x4 acc[8];
#pragma unroll
  for (int t = 0; t < 8; ++t) acc[t] = (f32x4){0.f, 0.f, 0.f, 0.f};
  __syncthreads();
#pragma unroll
  for (int t = 0; t < 8; ++t) {
    const unsigned short* Wr = &sWT[(t * 16 + ln) * 136 + q * 8];
    bf16x8 b0 = *(const bf16x8*)(Wr + 0);
    bf16x8 b1 = *(const bf16x8*)(Wr + 32);
    bf16x8 b2 = *(const bf16x8*)(Wr + 64);
    bf16x8 b3 = *(const bf16x8*)(Wr + 96);
    acc[t] = __builtin_amdgcn_mfma_f32_16x16x32_bf16(af0, b0, acc[t], 0, 0, 0);
    acc[t] = __builtin_amdgcn_mfma_f32_16x16x32_bf16(af1, b1, acc[t], 0, 0, 0);
    acc[t] = __builtin_amdgcn_mfma_f32_16x16x32_bf16(af2, b2, acc[t], 0, 0, 0);
    acc[t] = __builtin_amdgcn_mfma_f32_16x16x32_bf16(af3, b3, acc[t], 0, 0, 0);
  }
  float scl[4];
#pragma unroll
  for (int r = 0; r < 4; ++r) {
    scl[r] = 1.0f;
    if (MODE == 1) {
      int row = row0 + q * 4 + r;
      int rr = (row < N) ? row : 0;
      scl[r] = rsqrtf(fmaxf((float)deg_out[rr], 1.0f));
    }
  }
#pragma unroll
  for (int t = 0; t < 8; ++t) {
    float b = bias[t * 16 + ln];
#pragma unroll
    for (int r = 0; r < 4; ++r) {
      int row = row0 + q * 4 + r;
      if (row < N) {
        float v = (acc[t][r] + b) * scl[r];
        if (OUT_BF)
          outb[(size_t)row * 128 + t * 16 + ln] = (unsigned short)bf16rne(v);
        else
          outf[(size_t)row * 128 + t * 16 + ln] = v;
      }
    }
  }
}

// ---------------- launcher ----------------

extern "C" void kernel_launch(void* const* d_in, const int* in_sizes, int n_in,
                              void* d_out, int out_size, void* d_ws, size_t ws_size,
                              hipStream_t stream) {
  const float* x = (const float*)d_in[0];
  const float* W1 = (const float*)d_in[1];
  const float* b1 = (const float*)d_in[2];
  const float* W2 = (const float*)d_in[3];
  const float* b2 = (const float*)d_in[4];
  const float* W3 = (const float*)d_in[5];
  const float* b3 = (const float*)d_in[6];
  const int* src = (const int*)d_in[7];
  const int* dst = (const int*)d_in[8];
  float* out = (float*)d_out;

  const int N = NN;

  // workspace layout (~46 MB)
  unsigned short* hbf = (unsigned short*)d_ws;             // (NN+1)*D bf16
  unsigned short* aggB = hbf + (size_t)(NN + 1) * D;       // NN*D bf16
  unsigned short* WT1 = aggB + (size_t)NN * D;             // 128*128 bf16
  unsigned short* WT2 = WT1 + D * D;
  unsigned short* WT3 = WT2 + D * D;
  int* partial_dst = (int*)(WT3 + D * D);                  // CH*NN
  int* partial_src = partial_dst + (size_t)CH * NN;        // CH*NN
  int* degtmp = partial_src + (size_t)CH * NN;             // NN
  int* deg_out = degtmp + NN;                              // NN
  int* row_ptr = deg_out + NN;                             // NN+1
  int* partials = row_ptr + NN + 1;                        // 256
  int* csr_src = partials + 256;                           // CSRCAP

  const int scanBlocks = (N + 255) / 256;  // 196

  cvtw_kernel<<<6443, 256, 0, stream>>>(x, W1, W2, W3, hbf, WT1, WT2, WT3);
  hist_kernel<<<CH * RGH, 1024, 0, stream>>>(src, dst, partial_dst, partial_src);
  degscan_kernel<<<scanBlocks, 256, 0, stream>>>(partial_dst, partial_src, degtmp,
                                                 deg_out, row_ptr, partials, N);
  scan2<<<1, 256, 0, stream>>>(partials, row_ptr, scanBlocks, N);
  scan3<<<scanBlocks, 256, 0, stream>>>(row_ptr, partials, N);
  fill_kernel<<<CH * RGH, 1024, 0, stream>>>(src, dst, row_ptr, partial_dst, csr_src);
  pad_kernel<<<scanBlocks, 256, 0, stream>>>(row_ptr, degtmp, csr_src, N);

  int aggBlocks = (N + 3) / 4;
  int gemmBlocks = (N + 63) / 64;

  // layer 1: sage(x)
  agg_kernel<0><<<aggBlocks, 256, 0, stream>>>(hbf, row_ptr, csr_src, degtmp, aggB, N);
  mgemm_kernel<0, 1><<<gemmBlocks, 256, 0, stream>>>(aggB, WT1, b1, deg_out, nullptr, hbf, N);
  // layer 2: sage(h1); fold norm_out for layer 3 into epilogue
  agg_kernel<0><<<aggBlocks, 256, 0, stream>>>(hbf, row_ptr, csr_src, degtmp, aggB, N);
  mgemm_kernel<1, 1><<<gemmBlocks, 256, 0, stream>>>(aggB, WT2, b2, deg_out, nullptr, hbf, N);
  // layer 3: gcn: (agg(h2*norm_out) * norm_in) @ W3 + b3
  agg_kernel<1><<<aggBlocks, 256, 0, stream>>>(hbf, row_ptr, csr_src, degtmp, aggB, N);
  mgemm_kernel<0, 0><<<gemmBlocks, 256, 0, stream>>>(aggB, WT3, b3, deg_out, out, nullptr, N);
}

// Round 3
// 260.860 us; speedup vs baseline: 1.0820x; 1.0289x over previous
//
#include <hip/hip_runtime.h>

#define NN 50000
#define NE 800000
#define D 128

#define CH 32              // edge chunks
#define EPC (NE / CH)      // 25000 edges per chunk
#define RGH 4              // node ranges (160KB LDS lets us halve the passes)
#define NPRH (NN / RGH)    // 12500 nodes per range
#define CSRCAP (NE + 16 * NN)

#define HIST_BLOCKS (CH * RGH)  // 128
#define CVT_BLOCKS 1563         // ceil(1.6M / 1024)
#define WT_BLOCKS 48            // 3 matrices x 16384 / 1024

typedef short bf16x8 __attribute__((ext_vector_type(8)));
typedef float f32x4 __attribute__((ext_vector_type(4)));

// ---------------- bf16 helpers ----------------

__device__ __forceinline__ unsigned bf16rne(float f) {
  unsigned u = __float_as_uint(f);
  return (u + 0x7fffu + ((u >> 16) & 1u)) >> 16;
}
__device__ __forceinline__ unsigned packbf(float lo, float hi) {
  return bf16rne(lo) | (bf16rne(hi) << 16);
}

// fused: hist (blocks 0..127) | x->bf16 | W^T bf16 x3 | zero row NN
__global__ __launch_bounds__(1024) void cvtw_hist_kernel(
    const float* __restrict__ x, const float* __restrict__ W1,
    const float* __restrict__ W2, const float* __restrict__ W3,
    unsigned short* __restrict__ hbf, unsigned short* __restrict__ T1,
    unsigned short* __restrict__ T2, unsigned short* __restrict__ T3,
    const int* __restrict__ src, const int* __restrict__ dst,
    int* __restrict__ partial_dst, int* __restrict__ partial_src) {
  __shared__ int hd[NPRH];
  __shared__ int hs[NPRH];
  int b = blockIdx.x;
  int tid = threadIdx.x;
  if (b < HIST_BLOCKS) {
    int c = b >> 2;
    int r = b & 3;
    int base = r * NPRH;
    for (int i = tid; i < NPRH; i += 1024) { hd[i] = 0; hs[i] = 0; }
    __syncthreads();
    int e0 = c * EPC;
    for (int i = tid; i < EPC; i += 1024) {
      int d = dst[e0 + i];
      int s = src[e0 + i];
      unsigned dr = (unsigned)(d - base);
      unsigned sr = (unsigned)(s - base);
      if (dr < NPRH) atomicAdd(&hd[dr], 1);
      if (sr < NPRH) atomicAdd(&hs[sr], 1);
    }
    __syncthreads();
    for (int i = tid; i < NPRH; i += 1024) {
      partial_dst[c * NN + base + i] = hd[i];
      partial_src[c * NN + base + i] = hs[i];
    }
  } else if (b < HIST_BLOCKS + CVT_BLOCKS) {
    int i = (b - HIST_BLOCKS) * 1024 + tid;
    if (i < NN * D / 4) {
      float4 v = ((const float4*)x)[i];
      uint2 p;
      p.x = packbf(v.x, v.y);
      p.y = packbf(v.z, v.w);
      ((uint2*)hbf)[i] = p;
    }
  } else if (b < HIST_BLOCKS + CVT_BLOCKS + WT_BLOCKS) {
    int g = b - (HIST_BLOCKS + CVT_BLOCKS);
    int w = g >> 4;
    int i = (g & 15) * 1024 + tid;  // 0..16383
    const float* W = (w == 0) ? W1 : (w == 1) ? W2 : W3;
    unsigned short* T = (w == 0) ? T1 : (w == 1) ? T2 : T3;
    int n = i >> 7, k = i & 127;
    T[n * 128 + k] = (unsigned short)bf16rne(W[k * 128 + n]);
  } else {
    if (tid < 16) ((uint4*)(hbf + (size_t)NN * D))[tid] = make_uint4(0, 0, 0, 0);
  }
}

__device__ __forceinline__ int block_excl_scan(int v, int* wsum) {
  int lane = threadIdx.x & 63;
  int w = threadIdx.x >> 6;
  int incl = v;
#pragma unroll
  for (int off = 1; off < 64; off <<= 1) {
    int t = __shfl_up(incl, off);
    if (lane >= off) incl += t;
  }
  if (lane == 63) wsum[w] = incl;
  __syncthreads();
  int wo = 0;
#pragma unroll
  for (int j = 0; j < 4; ++j)
    if (j < w) wo += wsum[j];
  return wo + incl - v;
}

// fused reduce + scan phase 1: chunk-prefix partial_dst in place, true in-deg
// -> degtmp, out-deg -> deg_out, block-LOCAL exclusive scan of PADDED degree
// (ceil4) -> row_ptr, block totals -> partials. Consumers add partials[n>>8];
// no scan3 pass needed.
__global__ __launch_bounds__(256) void degscan_kernel(int* __restrict__ partial_dst,
                                                      const int* __restrict__ partial_src,
                                                      int* __restrict__ degtmp,
                                                      int* __restrict__ deg_out,
                                                      int* __restrict__ row_ptr,
                                                      int* __restrict__ partials, int N) {
  __shared__ int wsum[4];
  int d = blockIdx.x * 256 + threadIdx.x;
  int run = 0;
  if (d < N) {
#pragma unroll
    for (int c = 0; c < CH; ++c) {
      int v = partial_dst[c * NN + d];
      partial_dst[c * NN + d] = run;
      run += v;
    }
    degtmp[d] = run;
    int ro = 0;
#pragma unroll
    for (int c = 0; c < CH; ++c) ro += partial_src[c * NN + d];
    deg_out[d] = ro;
  }
  int pad = (run + 3) & ~3;
  int excl = block_excl_scan(pad, wsum);
  if (d <= N) row_ptr[d] = excl;  // d==N gets local end-of-block-195 prefix
  if (threadIdx.x == 255) partials[blockIdx.x] = excl + pad;
}

__global__ __launch_bounds__(256) void scan2(int* __restrict__ partials, int nb) {
  __shared__ int wsum[4];
  int v = (threadIdx.x < nb) ? partials[threadIdx.x] : 0;
  int excl = block_excl_scan(v, wsum);
  if (threadIdx.x < nb) partials[threadIdx.x] = excl;
}

// scatter fill; the last-chunk block also writes the NN-dummy pad tails
// (pad slots are disjoint from data slots, and this block's cur[] ends at
// row_start + deg exactly, so no inter-block ordering is needed).
__global__ __launch_bounds__(1024) void fill_kernel(const int* __restrict__ src,
                                                    const int* __restrict__ dst,
                                                    const int* __restrict__ row_ptr,
                                                    const int* __restrict__ partials,
                                                    const int* __restrict__ partial_dst,
                                                    int* __restrict__ csr_src) {
  __shared__ int cur[NPRH];
  int tid = threadIdx.x;
  int c = blockIdx.x >> 2;
  int r = blockIdx.x & 3;
  int base = r * NPRH;
  for (int i = tid; i < NPRH; i += 1024) {
    int nd = base + i;
    cur[i] = row_ptr[nd] + partials[nd >> 8] + partial_dst[c * NN + nd];
  }
  __syncthreads();
  int e0 = c * EPC;
  for (int i = tid; i < EPC; i += 1024) {
    int d = dst[e0 + i];
    unsigned dr = (unsigned)(d - base);
    if (dr < NPRH) {
      int pos = atomicAdd(&cur[dr], 1);
      csr_src[pos] = src[e0 + i];
    }
  }
  if (c == CH - 1) {
    __syncthreads();
    for (int i = tid; i < NPRH; i += 1024) {
      int nd = base + i;
      int s = cur[i];  // == global row start + deg
      int e = row_ptr[nd + 1] + partials[(nd + 1) >> 8];
      for (int j = s; j < e; ++j) csr_src[j] = NN;
    }
  }
}

// ---------------- aggregation: one QUARTER-WAVE (16 lanes) per node ---------
// Each lane owns 8 channels of one node; edges consumed 4 at a time via one
// int4 index load -> 16 row-loads in flight per wave (4x the old MLP), zero
// cross-lane shuffles. Rows padded to x4 with dummy index NN (zero row).
// bf16 in, f32 accumulate, bf16 out. MODE 0: sage. MODE 1: gcn rsqrt.
__device__ __forceinline__ void bacc(float* a, uint4 u) {
  a[0] += __uint_as_float(u.x << 16);
  a[1] += __uint_as_float(u.x & 0xffff0000u);
  a[2] += __uint_as_float(u.y << 16);
  a[3] += __uint_as_float(u.y & 0xffff0000u);
  a[4] += __uint_as_float(u.z << 16);
  a[5] += __uint_as_float(u.z & 0xffff0000u);
  a[6] += __uint_as_float(u.w << 16);
  a[7] += __uint_as_float(u.w & 0xffff0000u);
}

template <int MODE>
__global__ __launch_bounds__(256, 8) void agg_kernel(const unsigned short* __restrict__ hb,
                                                     const int* __restrict__ row_ptr,
                                                     const int* __restrict__ partials,
                                                     const int* __restrict__ csr_src,
                                                     const int* __restrict__ degtmp,
                                                     unsigned short* __restrict__ outb, int N) {
  int qw = threadIdx.x >> 4;   // 0..15: quarter-wave = node slot
  int col = threadIdx.x & 15;  // 16B granule within row
  int node = blockIdx.x * 16 + qw;
  if (node >= N) return;
  int start = row_ptr[node] + partials[node >> 8];
  int end = row_ptr[node + 1] + partials[(node + 1) >> 8];
  int indeg = degtmp[node];
  uint4 srow = make_uint4(0, 0, 0, 0);
  if (MODE == 0) srow = ((const uint4*)(hb + (size_t)node * D))[col];
  float a0[8] = {0, 0, 0, 0, 0, 0, 0, 0};
  float a1[8] = {0, 0, 0, 0, 0, 0, 0, 0};
  const int* ce = csr_src + start;
  int cnt = end - start;  // multiple of 4
  for (int it = 0; it < cnt; it += 4) {
    int4 ix = *(const int4*)(ce + it);
    uint4 u0 = ((const uint4*)(hb + (size_t)ix.x * D))[col];
    uint4 u1 = ((const uint4*)(hb + (size_t)ix.y * D))[col];
    uint4 u2 = ((const uint4*)(hb + (size_t)ix.z * D))[col];
    uint4 u3 = ((const uint4*)(hb + (size_t)ix.w * D))[col];
    bacc(a0, u0);
    bacc(a1, u1);
    bacc(a0, u2);
    bacc(a1, u3);
  }
#pragma unroll
  for (int j = 0; j < 8; ++j) a0[j] += a1[j];
  if (MODE == 0) {
    float sf[8] = {0, 0, 0, 0, 0, 0, 0, 0};
    bacc(sf, srow);
    float inv = 1.0f / (float)(indeg + 1);
#pragma unroll
    for (int j = 0; j < 8; ++j) a0[j] = (a0[j] + sf[j]) * inv;
  } else {
    float sc = rsqrtf(fmaxf((float)indeg, 1.0f));
#pragma unroll
    for (int j = 0; j < 8; ++j) a0[j] *= sc;
  }
  uint4 p;
  p.x = packbf(a0[0], a0[1]);
  p.y = packbf(a0[2], a0[3]);
  p.z = packbf(a0[4], a0[5]);
  p.w = packbf(a0[6], a0[7]);
  ((uint4*)(outb + (size_t)node * D))[col] = p;
}

// ---------------- MFMA GEMM: [N x 128](bf16) @ [128 x 128] + bias ------------
// 256 thr = 4 waves; block tile 64 rows; wave tile 16 rows x 128 cols.
// MODE 1: scale rows by rsqrt(max(deg_out,1)). OUT_BF 1: write bf16 table.
template <int MODE, int OUT_BF>
__global__ __launch_bounds__(256) void mgemm_kernel(const unsigned short* __restrict__ A,
                                                    const unsigned short* __restrict__ WT,
                                                    const float* __restrict__ bias,
                                                    const int* __restrict__ deg_out,
                                                    float* __restrict__ outf,
                                                    unsigned short* __restrict__ outb, int N) {
  __shared__ unsigned short sWT[128 * 136];
  int tid = threadIdx.x;
  for (int g = tid; g < 2048; g += 256) {
    int n = g >> 4, c = g & 15;
    uint4 v = ((const uint4*)WT)[g];
    *(uint4*)&sWT[n * 136 + c * 8] = v;
  }
  int wv = tid >> 6;
  int lane = tid & 63;
  int q = lane >> 4;
  int ln = lane & 15;
  int row0 = blockIdx.x * 64 + wv * 16;
  int arow = row0 + ln;
  if (arow >= N) arow = 0;  // clamp; stores are guarded
  const unsigned short* Ar = A + (size_t)arow * 128 + q * 8;
  bf16x8 af0 = *(const bf16x8*)(Ar + 0);
  bf16x8 af1 = *(const bf16x8*)(Ar + 32);
  bf16x8 af2 = *(const bf16x8*)(Ar + 64);
  bf16x8 af3 = *(const bf16x8*)(Ar + 96);
  f32x4 acc[8];
#pragma unroll
  for (int t = 0; t < 8; ++t) acc[t] = (f32x4){0.f, 0.f, 0.f, 0.f};
  __syncthreads();
#pragma unroll
  for (int t = 0; t < 8; ++t) {
    const unsigned short* Wr = &sWT[(t * 16 + ln) * 136 + q * 8];
    bf16x8 b0 = *(const bf16x8*)(Wr + 0);
    bf16x8 b1 = *(const bf16x8*)(Wr + 32);
    bf16x8 b2 = *(const bf16x8*)(Wr + 64);
    bf16x8 b3 = *(const bf16x8*)(Wr + 96);
    acc[t] = __builtin_amdgcn_mfma_f32_16x16x32_bf16(af0, b0, acc[t], 0, 0, 0);
    acc[t] = __builtin_amdgcn_mfma_f32_16x16x32_bf16(af1, b1, acc[t], 0, 0, 0);
    acc[t] = __builtin_amdgcn_mfma_f32_16x16x32_bf16(af2, b2, acc[t], 0, 0, 0);
    acc[t] = __builtin_amdgcn_mfma_f32_16x16x32_bf16(af3, b3, acc[t], 0, 0, 0);
  }
  float scl[4];
#pragma unroll
  for (int r = 0; r < 4; ++r) {
    scl[r] = 1.0f;
    if (MODE == 1) {
      int row = row0 + q * 4 + r;
      int rr = (row < N) ? row : 0;
      scl[r] = rsqrtf(fmaxf((float)deg_out[rr], 1.0f));
    }
  }
#pragma unroll
  for (int t = 0; t < 8; ++t) {
    float b = bias[t * 16 + ln];
#pragma unroll
    for (int r = 0; r < 4; ++r) {
      int row = row0 + q * 4 + r;
      if (row < N) {
        float v = (acc[t][r] + b) * scl[r];
        if (OUT_BF)
          outb[(size_t)row * 128 + t * 16 + ln] = (unsigned short)bf16rne(v);
        else
          outf[(size_t)row * 128 + t * 16 + ln] = v;
      }
    }
  }
}

// ---------------- launcher ----------------

extern "C" void kernel_launch(void* const* d_in, const int* in_sizes, int n_in,
                              void* d_out, int out_size, void* d_ws, size_t ws_size,
                              hipStream_t stream) {
  const float* x = (const float*)d_in[0];
  const float* W1 = (const float*)d_in[1];
  const float* b1 = (const float*)d_in[2];
  const float* W2 = (const float*)d_in[3];
  const float* b2 = (const float*)d_in[4];
  const float* W3 = (const float*)d_in[5];
  const float* b3 = (const float*)d_in[6];
  const int* src = (const int*)d_in[7];
  const int* dst = (const int*)d_in[8];
  float* out = (float*)d_out;

  const int N = NN;

  // workspace layout (~46 MB)
  unsigned short* hbf = (unsigned short*)d_ws;             // (NN+1)*D bf16
  unsigned short* aggB = hbf + (size_t)(NN + 1) * D;       // NN*D bf16
  unsigned short* WT1 = aggB + (size_t)NN * D;             // 128*128 bf16
  unsigned short* WT2 = WT1 + D * D;
  unsigned short* WT3 = WT2 + D * D;
  int* partial_dst = (int*)(WT3 + D * D);                  // CH*NN
  int* partial_src = partial_dst + (size_t)CH * NN;        // CH*NN
  int* degtmp = partial_src + (size_t)CH * NN;             // NN
  int* deg_out = degtmp + NN;                              // NN
  int* row_ptr = deg_out + NN;                             // NN+1
  int* partials = row_ptr + NN + 1;                        // 256
  int* csr_src = partials + 256;                           // CSRCAP

  const int scanBlocks = (N + 255) / 256;  // 196

  cvtw_hist_kernel<<<HIST_BLOCKS + CVT_BLOCKS + WT_BLOCKS + 1, 1024, 0, stream>>>(
      x, W1, W2, W3, hbf, WT1, WT2, WT3, src, dst, partial_dst, partial_src);
  degscan_kernel<<<scanBlocks, 256, 0, stream>>>(partial_dst, partial_src, degtmp,
                                                 deg_out, row_ptr, partials, N);
  scan2<<<1, 256, 0, stream>>>(partials, scanBlocks);
  fill_kernel<<<CH * RGH, 1024, 0, stream>>>(src, dst, row_ptr, partials, partial_dst,
                                             csr_src);

  int aggBlocks = (N + 15) / 16;  // 3125
  int gemmBlocks = (N + 63) / 64;

  // layer 1: sage(x)
  agg_kernel<0><<<aggBlocks, 256, 0, stream>>>(hbf, row_ptr, partials, csr_src, degtmp,
                                               aggB, N);
  mgemm_kernel<0, 1><<<gemmBlocks, 256, 0, stream>>>(aggB, WT1, b1, deg_out, nullptr, hbf, N);
  // layer 2: sage(h1); fold norm_out for layer 3 into epilogue
  agg_kernel<0><<<aggBlocks, 256, 0, stream>>>(hbf, row_ptr, partials, csr_src, degtmp,
                                               aggB, N);
  mgemm_kernel<1, 1><<<gemmBlocks, 256, 0, stream>>>(aggB, WT2, b2, deg_out, nullptr, hbf, N);
  // layer 3: gcn: (agg(h2*norm_out) * norm_in) @ W3 + b3
  agg_kernel<1><<<aggBlocks, 256, 0, stream>>>(hbf, row_ptr, partials, csr_src, degtmp,
                                               aggB, N);
  mgemm_kernel<0, 0><<<gemmBlocks, 256, 0, stream>>>(aggB, WT3, b3, deg_out, out, nullptr, N);
}